// Round 1
// baseline (740.567 us; speedup 1.0000x reference)
//
#include <hip/hip_runtime.h>

#define BATCH 2
#define CH    128
#define HH    64
#define WW    96
#define MD    40
#define KD    81
#define HW    (HH*WW)      /* 6144 */
#define CHW   (CH*HW)
#define SCALE 0.08838834764831845f   /* 1/sqrt(128) */

// One workgroup per (y, dy, b). 192 threads = 3 waves.
// Valid rows: stage x1[y] and x2[y2] rows in LDS ([c][x], two 64-ch halves),
// 132 register tiles of 8x (x) by 8 (dx).
__global__ __launch_bounds__(192) void corr_kernel(
    const float* __restrict__ x1, const float* __restrict__ x2,
    float* __restrict__ out)
{
    const int y   = blockIdx.x;
    const int dy  = blockIdx.y;
    const int b   = blockIdx.z;
    const int tid = threadIdx.x;

    float* outbase = out + ((size_t)b * (KD * KD) + (size_t)dy * KD) * HW
                         + (size_t)y * WW;

    const int y2 = y + dy - MD;
    if (y2 < 0 || y2 >= HH) {
        // whole 81 x 96 slab is zero (row displacement out of bounds)
        const float4 z = make_float4(0.f, 0.f, 0.f, 0.f);
        for (int f = tid; f < KD * (WW / 4); f += 192) {
            const int dx = f / (WW / 4);
            const int x4 = f - dx * (WW / 4);
            *reinterpret_cast<float4*>(outbase + (size_t)dx * HW + x4 * 4) = z;
        }
        return;
    }

    __shared__ float sA[64 * WW];   // 24 KB, layout [c_local][x]
    __shared__ float sB[64 * WW];   // 24 KB

    const float* x1p = x1 + (size_t)b * CHW + (size_t)y  * WW;
    const float* x2p = x2 + (size_t)b * CHW + (size_t)y2 * WW;

    // 12 x-tiles (8 wide) x 11 dx-tiles (8 wide) = 132 jobs; tids >=132 idle in compute
    const int xt  = tid % 12;
    const int dt  = tid / 12;
    const int x0  = xt * 8;
    const int dx0 = dt * 8;
    const int x20 = x0 + dx0 - MD;   // multiple of 8 -> float4 blocks 4-aligned
    // Clamp block starts; since all block starts are =0 mod 4, any block that
    // crosses [0,96) boundary is FULLY invalid -> clamped garbage is masked at write.
    const int bs0 = min(max(x20     , 0), WW - 4);
    const int bs1 = min(max(x20 +  4, 0), WW - 4);
    const int bs2 = min(max(x20 +  8, 0), WW - 4);
    const int bs3 = min(max(x20 + 12, 0), WW - 4);

    float acc[8][8];
    #pragma unroll
    for (int i = 0; i < 8; ++i)
        #pragma unroll
        for (int j = 0; j < 8; ++j) acc[i][j] = 0.f;

    for (int h = 0; h < 2; ++h) {
        if (h) __syncthreads();
        const float* g1 = x1p + (size_t)h * 64 * HW;
        const float* g2 = x2p + (size_t)h * 64 * HW;
        for (int t = tid; t < 64 * (WW / 4); t += 192) {   // 1536 float4, 8 iters
            const int c  = t / (WW / 4);
            const int x4 = (t - c * (WW / 4)) * 4;
            *reinterpret_cast<float4*>(sA + c * WW + x4) =
                *reinterpret_cast<const float4*>(g1 + (size_t)c * HW + x4);
            *reinterpret_cast<float4*>(sB + c * WW + x4) =
                *reinterpret_cast<const float4*>(g2 + (size_t)c * HW + x4);
        }
        __syncthreads();

        if (tid < 132) {
            #pragma unroll 4
            for (int c = 0; c < 64; ++c) {
                const float* rA = sA + c * WW;
                const float* rB = sB + c * WW;
                float a[8], bb[16];
                *reinterpret_cast<float4*>(a)     = *reinterpret_cast<const float4*>(rA + x0);
                *reinterpret_cast<float4*>(a + 4) = *reinterpret_cast<const float4*>(rA + x0 + 4);
                *reinterpret_cast<float4*>(bb)      = *reinterpret_cast<const float4*>(rB + bs0);
                *reinterpret_cast<float4*>(bb + 4)  = *reinterpret_cast<const float4*>(rB + bs1);
                *reinterpret_cast<float4*>(bb + 8)  = *reinterpret_cast<const float4*>(rB + bs2);
                *reinterpret_cast<float4*>(bb + 12) = *reinterpret_cast<const float4*>(rB + bs3);
                #pragma unroll
                for (int i = 0; i < 8; ++i)
                    #pragma unroll
                    for (int j = 0; j < 8; ++j)
                        acc[i][j] += a[i] * bb[i + j];   // bb[i+j] <-> x2 = x20+i+j
            }
        }
    }

    if (tid < 132) {
        #pragma unroll
        for (int j = 0; j < 8; ++j) {
            const int dx = dx0 + j;
            if (dx >= KD) break;              // only dt==10, j>0
            float v[8];
            #pragma unroll
            for (int i = 0; i < 8; ++i) {
                const int xx2 = x0 + i + dx - MD;
                v[i] = (xx2 >= 0 && xx2 < WW) ? acc[i][j] * SCALE : 0.f;
            }
            float* dst = outbase + (size_t)dx * HW + x0;
            *reinterpret_cast<float4*>(dst)     = *reinterpret_cast<const float4*>(v);
            *reinterpret_cast<float4*>(dst + 4) = *reinterpret_cast<const float4*>(v + 4);
        }
    }
}

extern "C" void kernel_launch(void* const* d_in, const int* in_sizes, int n_in,
                              void* d_out, int out_size, void* d_ws, size_t ws_size,
                              hipStream_t stream) {
    const float* x1 = (const float*)d_in[0];
    const float* x2 = (const float*)d_in[1];
    float* out = (float*)d_out;
    dim3 grid(HH, KD, BATCH);   // y, dy, b
    hipLaunchKernelGGL(corr_kernel, grid, dim3(192), 0, stream, x1, x2, out);
}

// Round 2
// 393.632 us; speedup vs baseline: 1.8814x; 1.8814x over previous
//
#include <hip/hip_runtime.h>

#define CH    128
#define HH    64
#define WW    96
#define MD    40
#define KD    81
#define HW    (HH*WW)          /* 6144 */
#define CHW   (CH*HW)
#define SCALE 0.08838834764831845f   /* 1/sqrt(128) */
#define LSTR  72               /* ushorts per LDS row: 64 bf16 + 8 pad (16B-aligned rows) */

typedef __attribute__((ext_vector_type(8))) short bf16x8;
typedef __attribute__((ext_vector_type(4))) float f32x4;

__device__ inline unsigned int pack2bf(float lo, float hi) {
    unsigned int a = __float_as_uint(lo), b = __float_as_uint(hi);
    a = (a + 0x7FFFu + ((a >> 16) & 1u)) >> 16;   // RTN bf16
    b = (b + 0x7FFFu + ((b >> 16) & 1u)) >> 16;
    return a | (b << 16);
}

// One workgroup per (y, dy, b); 256 threads = 4 waves.
// Valid rows: G[x2][x] = sum_c x1[c][x]*x2[c][x2] via 16x16x32 bf16 MFMA,
// then LDS round-trip to emit banded diagonals coalesced.
__global__ __launch_bounds__(256, 4) void corr_kernel(
    const float* __restrict__ x1, const float* __restrict__ x2,
    float* __restrict__ out)
{
    const int y   = blockIdx.x;
    const int dy  = blockIdx.y;
    const int b   = blockIdx.z;
    const int tid = threadIdx.x;

    float* outbase = out + ((size_t)b * (KD * KD) + (size_t)dy * KD) * HW
                         + (size_t)y * WW;

    const int y2 = y + dy - MD;
    if (y2 < 0 || y2 >= HH) {
        const float4 z = make_float4(0.f, 0.f, 0.f, 0.f);
        for (int f = tid; f < KD * (WW / 4); f += 256) {
            const int dx = f / (WW / 4);
            const int x4 = f - dx * (WW / 4);
            *reinterpret_cast<float4*>(outbase + (size_t)dx * HW + x4 * 4) = z;
        }
        return;
    }

    // Union LDS: staging (2 x 96 x 72 ushorts = 27648 B) overlapped with
    // G (96x96 fp32 = 36864 B). Total 36864 B -> 4 blocks/CU.
    __shared__ __align__(16) char smem[WW * WW * 4];
    unsigned short* sA = reinterpret_cast<unsigned short*>(smem);   // x1 row, [x][c-half]
    unsigned short* sB = sA + WW * LSTR;                            // x2 row, [x2][c-half]
    float*          sG = reinterpret_cast<float*>(smem);            // G[x2][x]

    const float* x1p = x1 + (size_t)b * CHW + (size_t)y  * WW;
    const float* x2p = x2 + (size_t)b * CHW + (size_t)y2 * WW;

    const int lane = tid & 63;
    const int wave = tid >> 6;
    const int m0   = (wave >> 1) * 48;   // x2-tile base for this wave
    const int n0   = (wave & 1) * 48;    // x-tile base
    const int lr   = lane & 15;
    const int q    = lane >> 4;

    f32x4 acc[3][3];
    #pragma unroll
    for (int i = 0; i < 3; ++i)
        #pragma unroll
        for (int j = 0; j < 3; ++j)
            acc[i][j] = (f32x4){0.f, 0.f, 0.f, 0.f};

    for (int h = 0; h < 2; ++h) {
        if (h) __syncthreads();          // protect half-0 fragment reads
        const float* g1 = x1p + (size_t)h * 64 * HW;
        const float* g2 = x2p + (size_t)h * 64 * HW;
        // stage 64 channels of both rows as bf16, transposed to [x][c]
        for (int j = tid; j < 768; j += 256) {      // 3 iters
            const int x  = j % WW;
            const int cg = j / WW;                  // 0..7, 8 channels each
            const float* p1 = g1 + (size_t)(cg * 8) * HW + x;
            const float* p2 = g2 + (size_t)(cg * 8) * HW + x;
            float f1[8], f2[8];
            #pragma unroll
            for (int i = 0; i < 8; ++i) { f1[i] = p1[(size_t)i * HW]; f2[i] = p2[(size_t)i * HW]; }
            uint4 w1, w2;
            w1.x = pack2bf(f1[0], f1[1]); w1.y = pack2bf(f1[2], f1[3]);
            w1.z = pack2bf(f1[4], f1[5]); w1.w = pack2bf(f1[6], f1[7]);
            w2.x = pack2bf(f2[0], f2[1]); w2.y = pack2bf(f2[2], f2[3]);
            w2.z = pack2bf(f2[4], f2[5]); w2.w = pack2bf(f2[6], f2[7]);
            *reinterpret_cast<uint4*>(&sA[x * LSTR + cg * 8]) = w1;
            *reinterpret_cast<uint4*>(&sB[x * LSTR + cg * 8]) = w2;
        }
        __syncthreads();

        #pragma unroll
        for (int kk = 0; kk < 2; ++kk) {
            const int cl = kk * 32 + q * 8;         // k-offset within this half
            bf16x8 af[3], bg[3];
            #pragma unroll
            for (int i = 0; i < 3; ++i)
                af[i] = *reinterpret_cast<const bf16x8*>(&sB[(m0 + 16 * i + lr) * LSTR + cl]);
            #pragma unroll
            for (int j = 0; j < 3; ++j)
                bg[j] = *reinterpret_cast<const bf16x8*>(&sA[(n0 + 16 * j + lr) * LSTR + cl]);
            #pragma unroll
            for (int i = 0; i < 3; ++i)
                #pragma unroll
                for (int j = 0; j < 3; ++j)
                    acc[i][j] = __builtin_amdgcn_mfma_f32_16x16x32_bf16(
                        af[i], bg[j], acc[i][j], 0, 0, 0);
        }
    }

    __syncthreads();                     // all fragment reads done; smem becomes G
    // D layout: col = lane&15 (=x), row = q*4+r (=x2 within tile)
    #pragma unroll
    for (int i = 0; i < 3; ++i) {
        #pragma unroll
        for (int j = 0; j < 3; ++j) {
            const int col  = n0 + 16 * j + lr;
            const int rowb = m0 + 16 * i + q * 4;
            #pragma unroll
            for (int r = 0; r < 4; ++r)
                sG[(rowb + r) * WW + col] = acc[i][j][r];
        }
    }
    __syncthreads();

    // Emit 81 x 96 slab: out[dx][x] = G[x+dx-40][x] * SCALE (0 outside band).
    // Diagonal LDS reads: addr = 97*x + const, 97 % 32 == 1 -> conflict-free.
    for (int j = tid; j < KD * WW; j += 256) {      // ~30 iters
        const int dx = j / WW;
        const int x  = j - dx * WW;
        const int x2 = x + dx - MD;
        const float v = (x2 >= 0 && x2 < WW) ? sG[x2 * WW + x] * SCALE : 0.f;
        outbase[(size_t)dx * HW + x] = v;
    }
}

extern "C" void kernel_launch(void* const* d_in, const int* in_sizes, int n_in,
                              void* d_out, int out_size, void* d_ws, size_t ws_size,
                              hipStream_t stream) {
    const float* x1 = (const float*)d_in[0];
    const float* x2 = (const float*)d_in[1];
    float* out = (float*)d_out;
    dim3 g(HH, KD, 2);   // y, dy, b
    hipLaunchKernelGGL(corr_kernel, g, dim3(256), 0, stream, x1, x2, out);
}